// Round 4
// baseline (17915.517 us; speedup 1.0000x reference)
//
#include <hip/hip_runtime.h>
#include <hip/hip_bf16.h>

#define EMBED   1024
#define HIDDEN  2048
#define G4      8192   // 4*HIDDEN
#define LENGTH  4096

typedef unsigned int   u32;
typedef unsigned short u16;
typedef __attribute__((ext_vector_type(4))) float f32x4;
typedef __attribute__((ext_vector_type(8))) short short8;

__device__ __forceinline__ u16 f2bf(float x){
  __hip_bfloat16 h = __float2bfloat16(x);   // RNE
  return __builtin_bit_cast(u16, h);
}
__device__ __forceinline__ float bf2f(u16 b){
  return __uint_as_float(((u32)b) << 16);
}

#if __has_builtin(__builtin_amdgcn_fdot2_f32_bf16)
typedef __attribute__((ext_vector_type(2))) __bf16 bf16x2;
__device__ __forceinline__ float dot2acc(u32 a, u32 b, float c){
  return __builtin_amdgcn_fdot2_f32_bf16(__builtin_bit_cast(bf16x2, a),
                                         __builtin_bit_cast(bf16x2, b), c, false);
}
#else
__device__ __forceinline__ float dot2acc(u32 a, u32 b, float c){
  float r = c;
  r += __uint_as_float(a << 16)          * __uint_as_float(b << 16);
  r += __uint_as_float(a & 0xffff0000u)  * __uint_as_float(b & 0xffff0000u);
  return r;
}
#endif

__device__ __forceinline__ float fsig(float x){ return 1.f/(1.f + __expf(-x)); }
__device__ __forceinline__ float ftanh_(float x){ return 1.f - 2.f/(1.f + __expf(2.f*x)); }

// ---------------- fp32 -> bf16 conversion (vectorized) ----------------
__global__ void conv_bf16(const float* __restrict__ src, u16* __restrict__ dst, int n4){
  int i = blockIdx.x * blockDim.x + threadIdx.x;
  if (i < n4){
    float4 v = reinterpret_cast<const float4*>(src)[i];
    ushort4 o;
    o.x = f2bf(v.x); o.y = f2bf(v.y); o.z = f2bf(v.z); o.w = f2bf(v.w);
    reinterpret_cast<ushort4*>(dst)[i] = o;
  }
}

// ---------------- x_proj GEMM: out[m][j][g] = sum_k A[m][k]*B[g*2048+j][k] + bias ----------------
__global__ __launch_bounds__(256) void gemm_xproj(
    const u16* __restrict__ A, const u16* __restrict__ B,
    const float* __restrict__ b_ih, const float* __restrict__ b_hh,
    u16* __restrict__ C)
{
  __shared__ __align__(16) u16 As[64][40];
  __shared__ __align__(16) u16 Bs[64][40];
  const int tid  = threadIdx.x;
  const int lane = tid & 63, wid = tid >> 6;
  const int wr = wid >> 1, wc = wid & 1;
  const int m0 = blockIdx.y * 64, n0 = blockIdx.x * 64;
  const int srow = tid >> 2, sseg = (tid & 3) * 8;

  f32x4 acc[2][2] = {};
  for (int k0 = 0; k0 < EMBED; k0 += 32){
    *(short8*)&As[srow][sseg] = *(const short8*)&A[(size_t)(m0 + srow) * EMBED + k0 + sseg];
    *(short8*)&Bs[srow][sseg] = *(const short8*)&B[(size_t)(n0 + srow) * EMBED + k0 + sseg];
    __syncthreads();
    const int rr = lane & 15, kg = (lane >> 4) * 8;
    #pragma unroll
    for (int mi = 0; mi < 2; ++mi){
      short8 a = *(const short8*)&As[wr*32 + mi*16 + rr][kg];
      #pragma unroll
      for (int ni = 0; ni < 2; ++ni){
        short8 b = *(const short8*)&Bs[wc*32 + ni*16 + rr][kg];
        acc[mi][ni] = __builtin_amdgcn_mfma_f32_16x16x32_bf16(a, b, acc[mi][ni], 0, 0, 0);
      }
    }
    __syncthreads();
  }
  const int rr = lane & 15, rg = (lane >> 4) * 4;
  #pragma unroll
  for (int ni = 0; ni < 2; ++ni){
    int n = n0 + wc*32 + ni*16 + rr;      // n = gate*2048 + j
    int g = n >> 11, j = n & 2047;
    float bias = b_ih[n] + b_hh[n];
    #pragma unroll
    for (int mi = 0; mi < 2; ++mi){
      #pragma unroll
      for (int r = 0; r < 4; ++r){
        int m = m0 + wr*32 + mi*16 + rg + r;
        C[(size_t)m * G4 + j*4 + g] = f2bf(acc[mi][ni][r] + bias);
      }
    }
  }
}

// ---------------- persistent LSTM scan ----------------
// 256 WGs x 512 threads. Wave w of WG wg owns hidden unit j = wg*8 + w.
// W_hh slice held in 64 NAMED scalar u32 (packed bf16 pairs) per lane --
// named scalars are SSA at SROA time (arrays were demoted to scratch in
// rounds 2/3: VGPR_Count 56/48, weights re-read from L2 every step).
// asm "+v" pins each against rematerialization. (512,2) -> 256 VGPR budget.
// Mapping: lane l, read r covers columns r*512 + l*8 + {0..7}; word q of
// read r = columns r*512+l*8+2q,+1. h_bf[r][i] = h[r*512+i].
#define PK2(x,y) ((u32)f2bf(x) | ((u32)f2bf(y) << 16))

#define DECL16(g) u32 w##g##_0, w##g##_1, w##g##_2,  w##g##_3,  w##g##_4,  w##g##_5,  w##g##_6,  w##g##_7, \
                      w##g##_8, w##g##_9, w##g##_10, w##g##_11, w##g##_12, w##g##_13, w##g##_14, w##g##_15

#define STAGE_GATE(g) { \
  const float* row_ = Whh + (size_t)((g)*HIDDEN + jrow) * HIDDEN + lane*8; \
  float4 a_, b_; \
  a_ = *(const float4*)(row_ +    0); b_ = *(const float4*)(row_ +    4); \
  w##g##_0  = PK2(a_.x,a_.y); w##g##_1  = PK2(a_.z,a_.w); w##g##_2  = PK2(b_.x,b_.y); w##g##_3  = PK2(b_.z,b_.w); \
  a_ = *(const float4*)(row_ +  512); b_ = *(const float4*)(row_ +  516); \
  w##g##_4  = PK2(a_.x,a_.y); w##g##_5  = PK2(a_.z,a_.w); w##g##_6  = PK2(b_.x,b_.y); w##g##_7  = PK2(b_.z,b_.w); \
  a_ = *(const float4*)(row_ + 1024); b_ = *(const float4*)(row_ + 1028); \
  w##g##_8  = PK2(a_.x,a_.y); w##g##_9  = PK2(a_.z,a_.w); w##g##_10 = PK2(b_.x,b_.y); w##g##_11 = PK2(b_.z,b_.w); \
  a_ = *(const float4*)(row_ + 1536); b_ = *(const float4*)(row_ + 1540); \
  w##g##_12 = PK2(a_.x,a_.y); w##g##_13 = PK2(a_.z,a_.w); w##g##_14 = PK2(b_.x,b_.y); w##g##_15 = PK2(b_.z,b_.w); }

#define OPQ(x) asm volatile("" : "+v"(x))
#define OPQ16(g) { OPQ(w##g##_0); OPQ(w##g##_1); OPQ(w##g##_2);  OPQ(w##g##_3); \
                   OPQ(w##g##_4); OPQ(w##g##_5); OPQ(w##g##_6);  OPQ(w##g##_7); \
                   OPQ(w##g##_8); OPQ(w##g##_9); OPQ(w##g##_10); OPQ(w##g##_11); \
                   OPQ(w##g##_12);OPQ(w##g##_13);OPQ(w##g##_14); OPQ(w##g##_15); }

#define DOT_GATE(acc, g) { \
  acc = dot2acc(w##g##_0,  ha.x, acc); acc = dot2acc(w##g##_1,  ha.y, acc); \
  acc = dot2acc(w##g##_2,  ha.z, acc); acc = dot2acc(w##g##_3,  ha.w, acc); \
  acc = dot2acc(w##g##_4,  hb.x, acc); acc = dot2acc(w##g##_5,  hb.y, acc); \
  acc = dot2acc(w##g##_6,  hb.z, acc); acc = dot2acc(w##g##_7,  hb.w, acc); \
  acc = dot2acc(w##g##_8,  hc.x, acc); acc = dot2acc(w##g##_9,  hc.y, acc); \
  acc = dot2acc(w##g##_10, hc.z, acc); acc = dot2acc(w##g##_11, hc.w, acc); \
  acc = dot2acc(w##g##_12, hd.x, acc); acc = dot2acc(w##g##_13, hd.y, acc); \
  acc = dot2acc(w##g##_14, hd.z, acc); acc = dot2acc(w##g##_15, hd.w, acc); }

__global__ __launch_bounds__(512, 2) void lstm_scan(
    const float* __restrict__ Whh,   // [8192][2048] fp32
    const u16*  __restrict__ xp,     // [4096][2048][4] bf16 (packed by gemm)
    u32* htag)                       // [2][2048]
{
  const int wg = blockIdx.x;
  const int tid = threadIdx.x;
  const int w = tid >> 6, lane = tid & 63;
  const int jrow = wg*8 + w;
  __shared__ __align__(16) u16 h_bf[4][512];

  DECL16(0); DECL16(1); DECL16(2); DECL16(3);
  STAGE_GATE(0); STAGE_GATE(1); STAGE_GATE(2); STAGE_GATE(3);
  OPQ16(0); OPQ16(1); OPQ16(2); OPQ16(3);

  float c_reg = 0.f;
  // software-pipelined x_proj prefetch: one 8B load per wave per step
  ushort4 xv_cur = {0,0,0,0}, xv_nxt = {0,0,0,0};
  if (lane == 0) xv_cur = *(const ushort4*)(xp + (size_t)0 * G4 + jrow * 4);

  for (int t = 0; t < LENGTH; ++t){
    if (lane == 0 && t + 1 < LENGTH)
      xv_nxt = *(const ushort4*)(xp + (size_t)(t + 1) * G4 + jrow * 4);

    // acquire step-t h (tag == t), buffer t&1; coalesced poll
    u32* src = htag + ((t & 1) << 11);
    const u32 want = (u32)t;
    u32 v0, v1, v2, v3;
    for (;;){
      v0 = __hip_atomic_load(&src[tid       ], __ATOMIC_RELAXED, __HIP_MEMORY_SCOPE_AGENT);
      v1 = __hip_atomic_load(&src[tid +  512], __ATOMIC_RELAXED, __HIP_MEMORY_SCOPE_AGENT);
      v2 = __hip_atomic_load(&src[tid + 1024], __ATOMIC_RELAXED, __HIP_MEMORY_SCOPE_AGENT);
      v3 = __hip_atomic_load(&src[tid + 1536], __ATOMIC_RELAXED, __HIP_MEMORY_SCOPE_AGENT);
      if ((v0 >> 16) == want && (v1 >> 16) == want &&
          (v2 >> 16) == want && (v3 >> 16) == want) break;
      __builtin_amdgcn_s_sleep(1);
    }
    h_bf[0][tid] = (u16)v0;
    h_bf[1][tid] = (u16)v1;
    h_bf[2][tid] = (u16)v2;
    h_bf[3][tid] = (u16)v3;
    __syncthreads();

    // 4 conflict-free ds_read_b128 (verified 0 conflicts in rounds 2/3)
    uint4 ha = *(const uint4*)&h_bf[0][lane*8];
    uint4 hb = *(const uint4*)&h_bf[1][lane*8];
    uint4 hc = *(const uint4*)&h_bf[2][lane*8];
    uint4 hd = *(const uint4*)&h_bf[3][lane*8];
    float a0 = 0.f, a1 = 0.f, a2 = 0.f, a3 = 0.f;
    DOT_GATE(a0, 0); DOT_GATE(a1, 1); DOT_GATE(a2, 2); DOT_GATE(a3, 3);
    #pragma unroll
    for (int m = 32; m >= 1; m >>= 1){
      a0 += __shfl_xor(a0, m, 64);
      a1 += __shfl_xor(a1, m, 64);
      a2 += __shfl_xor(a2, m, 64);
      a3 += __shfl_xor(a3, m, 64);
    }
    if (lane == 0){
      float gi = fsig (a0 + bf2f(xv_cur.x));
      float gf = fsig (a1 + bf2f(xv_cur.y));
      float gg = ftanh_(a2 + bf2f(xv_cur.z));
      float go = fsig (a3 + bf2f(xv_cur.w));
      c_reg = gf * c_reg + gi * gg;
      float h = go * ftanh_(c_reg);
      u32 word = ((u32)(t + 1) << 16) | (u32)f2bf(h);
      __hip_atomic_store(&htag[(((t + 1) & 1) << 11) + jrow], word,
                         __ATOMIC_RELAXED, __HIP_MEMORY_SCOPE_AGENT);
    }
    xv_cur = xv_nxt;
    // single barrier per step: publish(t+1) gated by the barrier above implies
    // all threads of this WG consumed step-t h before any producer can reach
    // step t+2 and overwrite this parity buffer.
  }
}

// ---------------- final head: sigmoid(h . W_fc + b_fc) ----------------
__global__ __launch_bounds__(256) void head_k(const u32* __restrict__ htag,
                                              const float* __restrict__ Wfc,
                                              const float* __restrict__ bfc,
                                              float* __restrict__ out){
  __shared__ float red[256];
  int tid = threadIdx.x;
  float s = 0.f;
  #pragma unroll
  for (int k = 0; k < 8; ++k){
    int j = tid * 8 + k;
    s += bf2f((u16)(htag[j] & 0xffffu)) * Wfc[j];   // tag 4096 lives in buffer 0
  }
  red[tid] = s;
  __syncthreads();
  for (int k = 128; k > 0; k >>= 1){
    if (tid < k) red[tid] += red[tid + k];
    __syncthreads();
  }
  if (tid == 0) out[0] = 1.f / (1.f + __expf(-(red[0] + bfc[0])));
}

// ---------------- launch ----------------
extern "C" void kernel_launch(void* const* d_in, const int* in_sizes, int n_in,
                              void* d_out, int out_size, void* d_ws, size_t ws_size,
                              hipStream_t stream){
  const float* x   = (const float*)d_in[0];   // [1,4096,1024]
  const float* Wih = (const float*)d_in[1];   // [8192,1024]
  const float* Whh = (const float*)d_in[2];   // [8192,2048]
  const float* bih = (const float*)d_in[3];   // [8192]
  const float* bhh = (const float*)d_in[4];   // [8192]
  const float* Wfc = (const float*)d_in[5];   // [1,2048]
  const float* bfc = (const float*)d_in[6];   // [1]
  float* out = (float*)d_out;

  char* ws = (char*)d_ws;
  u16* xp     = (u16*)(ws);                    // 4096*8192*2 = 67108864
  u16* x_bf   = (u16*)(ws + 67108864);         // 8388608
  u16* wih_bf = (u16*)(ws + 75497472);         // 16777216
  u32* htag   = (u32*)(ws + 92274688);         // 2*2048*4 = 16384

  hipMemsetAsync(htag, 0, 2 * HIDDEN * sizeof(u32), stream);
  conv_bf16<<<(EMBED*LENGTH/4 + 255)/256, 256, 0, stream>>>(x, x_bf, EMBED*LENGTH/4);
  conv_bf16<<<(G4*EMBED/4 + 255)/256, 256, 0, stream>>>(Wih, wih_bf, G4*EMBED/4);
  dim3 gg(G4/64, LENGTH/64);
  gemm_xproj<<<gg, 256, 0, stream>>>(x_bf, wih_bf, bih, bhh, xp);
  lstm_scan<<<256, 512, 0, stream>>>(Whh, xp, htag);
  head_k<<<1, 256, 0, stream>>>(htag, Wfc, bfc, out);
}